// Round 6
// baseline (202.915 us; speedup 1.0000x reference)
//
#include <hip/hip_runtime.h>
#include <hip/hip_bf16.h>
#include <stdint.h>

typedef int i32x4 __attribute__((ext_vector_type(4)));

// ---------------- exact-math helpers (match XLA/np f32 semantics) -----------

__device__ __forceinline__ float xla_erf(float x) {
#pragma clang fp contract(off)
  x = fminf(3.832506856900711f, fmaxf(-3.832506856900711f, x));
  float x2 = x * x;
  float p = -2.72614225801306e-10f;
  p = p * x2 + 2.77068142495902e-08f;
  p = p * x2 + -2.10102402082508e-06f;
  p = p * x2 + -5.69250639462346e-05f;
  p = p * x2 + -7.34990630326855e-04f;
  p = p * x2 + -2.95459980854025e-03f;
  p = p * x2 + -1.60960333262415e-02f;
  p = x * p;
  float q = -1.45660718464996e-05f;
  q = q * x2 + -2.13374055278905e-04f;
  q = q * x2 + -1.68282697438203e-03f;
  q = q * x2 + -7.37332916720468e-03f;
  q = q * x2 + -1.42647390514189e-02f;
  return p / q;
}

__device__ __forceinline__ float gelu_exact(float x) {
#pragma clang fp contract(off)
  float t = x / 1.41421356237309504880f;
  float e = xla_erf(t);
  float u = e + 1.0f;
  float v = x * u;
  return v * 0.5f;
}

__device__ __forceinline__ float epi_scale(float iacc, float sc, float b) {
#pragma clang fp contract(off)
  float v = iacc * sc;
  v = v + b;
  return v;
}

__device__ __forceinline__ int quant1(float x, float scale) {
#pragma clang fp contract(off)
  float t = x / scale;
  t = rintf(t);
  t = fmaxf(-8.0f, fminf(7.0f, t));
  return (int)t;
}

// ---------------- small kernels ---------------------------------------------

__global__ void init_kernel(unsigned* slots) {
  if (threadIdx.x < 4) slots[threadIdx.x] = 0u;
}

__global__ void absmax3(const float* __restrict__ p0, long n0,
                        const float* __restrict__ p1, long n1,
                        const float* __restrict__ p2, long n2,
                        unsigned* __restrict__ slots) {
  const int t = blockIdx.y;
  const float4* p = (const float4*)(t == 0 ? p0 : (t == 1 ? p1 : p2));
  const long n4 = (t == 0 ? n0 : (t == 1 ? n1 : n2));
  float m = 0.0f;
  long i = (long)blockIdx.x * blockDim.x + threadIdx.x;
  const long stride = (long)gridDim.x * blockDim.x;
  for (; i < n4; i += stride) {
    float4 v = p[i];
    m = fmaxf(m, fmaxf(fmaxf(fabsf(v.x), fabsf(v.y)), fmaxf(fabsf(v.z), fabsf(v.w))));
  }
  for (int o = 32; o > 0; o >>= 1) m = fmaxf(m, __shfl_xor(m, o));
  if ((threadIdx.x & 63) == 0) atomicMax(slots + t, __float_as_uint(m));
}

// fp32 [R][C] -> signed i8 [Rpad][ldq] (row stride ldq bytes, 64-aligned);
// bytes [C, C+segs) hold the per-segment signed AND-mask (ADC correction,
// sign=-1 for weights); [C+segs, ldq) zero. Padded rows fully zero.
__global__ void quant_kernel(const float* __restrict__ in, int R, int C, int ldq,
                             const unsigned* __restrict__ slot, int sign,
                             char* __restrict__ qout) {
  const int segs_per_row = C >> 8;
  const int seg = blockIdx.x * 4 + (threadIdx.x >> 6);
  const int lane = threadIdx.x & 63;
  const int r = seg / segs_per_row;
  const int s = seg - r * segs_per_row;
  const float scale = fmaxf(__uint_as_float(*slot) / 7.0f, 1e-8f);
  const size_t qbase = (size_t)r * ldq + (size_t)s * 256 + lane * 4;
  int mask = 0;
  if (r < R) {
    const size_t base = (size_t)r * C + (size_t)s * 256 + lane * 4;
    float4 v = *(const float4*)(in + base);
    int q0 = quant1(v.x, scale);
    int q1 = quant1(v.y, scale);
    int q2 = quant1(v.z, scale);
    int q3 = quant1(v.w, scale);
    unsigned pk = (q0 & 0xff) | ((q1 & 0xff) << 8) | ((q2 & 0xff) << 16) |
                  ((unsigned)(q3 & 0xff) << 24);
    *(unsigned*)(qout + qbase) = pk;
    mask = q0 & q1 & q2 & q3 & 15;
  } else {
    *(unsigned*)(qout + qbase) = 0u;
    mask = 0;
  }
  for (int o = 32; o > 0; o >>= 1) mask &= __shfl_xor(mask, o);
  if (lane == 0)
    qout[(size_t)r * ldq + C + s] = (char)(sign * ((mask & 7) - (mask & 8)));
  const int padw = ldq - C - segs_per_row;
  if (s == 0 && lane < padw)
    qout[(size_t)r * ldq + C + segs_per_row + lane] = 0;
}

// out = ((p0+p1)+(p2+p3)) * (s_h*s_w2) + b2  (exact ints, order-free)
__global__ void epi2_kernel(const float* __restrict__ partial, long cstride,
                            const float* __restrict__ b2,
                            const unsigned* __restrict__ slots,
                            float* __restrict__ out, long n4) {
  const float sa = fmaxf(__uint_as_float(slots[3]) / 7.0f, 1e-8f);
  const float sb = fmaxf(__uint_as_float(slots[2]) / 7.0f, 1e-8f);
  const float sc = sa * sb;
  long i = (long)blockIdx.x * blockDim.x + threadIdx.x;
  const long stride = (long)gridDim.x * blockDim.x;
  for (; i < n4; i += stride) {
    float4 v0 = ((const float4*)partial)[i];
    float4 v1 = ((const float4*)(partial + cstride))[i];
    float4 v2 = ((const float4*)(partial + 2 * cstride))[i];
    float4 v3 = ((const float4*)(partial + 3 * cstride))[i];
    float4 bb = ((const float4*)b2)[i % 192];  // 768/4
    float4 o;
    o.x = epi_scale((v0.x + v1.x) + (v2.x + v3.x), sc, bb.x);
    o.y = epi_scale((v0.y + v1.y) + (v2.y + v3.y), sc, bb.y);
    o.z = epi_scale((v0.z + v1.z) + (v2.z + v3.z), sc, bb.z);
    o.w = epi_scale((v0.w + v1.w) + (v2.w + v3.w), sc, bb.w);
    ((float4*)out)[i] = o;
  }
}

// ---------------- GEMM (i8, exact, register-direct, no LDS/barriers) --------
// Block = 4 independent waves (2x2), each owning a 64x64 output tile of a
// 128x128 block tile. Fragments load straight from global (i8 16x16x64
// fragment is 16 contiguous bytes per lane at row (lane&15), k=(lane>>4)*16 —
// layout verified by round-5 pass). L1 dedups the 2x-shared A/B panels.
// No __syncthreads, no LDS: waves schedule independently; compiler inserts
// counted waitcnts and pipelines the unrolled loop.
// MODE 0: epilogue scale+bias+gelu, store f32, fused absmax -> slots[3]
// MODE 1: split-K; chunk c stores exact-integer partials (as f32) per chunk.
template <int MODE>
__global__ __launch_bounds__(256) void gemm_cim(
    const char* __restrict__ A, const char* __restrict__ B,
    int Mstore, int ldq, int mtiles, int kbase, int krem,
    const unsigned* __restrict__ slots, int slotA, int slotB,
    const float* __restrict__ bias, float* __restrict__ outp, int ldo,
    long cstride) {
  const int tid = threadIdx.x;
  const int lane = tid & 63;
  const int wv = tid >> 6;
  const int bm = blockIdx.x % mtiles;
  const int bn = blockIdx.x / mtiles;
  const long m0 = (long)bm * 128;
  const long n0 = (long)bn * 128;
  const int chunk = blockIdx.y;
  const int k_begin = chunk * kbase + min(chunk, krem);  // in BK=64 units
  const int k_iters = kbase + (chunk < krem ? 1 : 0);

  const int wm = wv >> 1, wn = wv & 1;
  const int lr = lane & 15, kg = lane >> 4;

  const char* pA = A + (m0 + wm * 64 + lr) * (long)ldq + (long)k_begin * 64 + kg * 16;
  const char* pB = B + (n0 + wn * 64 + lr) * (long)ldq + (long)k_begin * 64 + kg * 16;
  const long fstride = 16 * (long)ldq;

  i32x4 acc[4][4] = {};

#pragma unroll 2
  for (int kt = 0; kt < k_iters; ++kt) {
    const long ko = (long)kt * 64;
    i32x4 av[4], bv[4];
#pragma unroll
    for (int f = 0; f < 4; ++f) av[f] = *(const i32x4*)(pA + f * fstride + ko);
#pragma unroll
    for (int f = 0; f < 4; ++f) bv[f] = *(const i32x4*)(pB + f * fstride + ko);
#pragma unroll
    for (int fa = 0; fa < 4; ++fa)
#pragma unroll
      for (int fb = 0; fb < 4; ++fb)
        acc[fa][fb] = __builtin_amdgcn_mfma_i32_16x16x64_i8(av[fa], bv[fb], acc[fa][fb], 0, 0, 0);
  }

  if (MODE == 0) {
    const float sa = fmaxf(__uint_as_float(slots[slotA]) / 7.0f, 1e-8f);
    const float sb = fmaxf(__uint_as_float(slots[slotB]) / 7.0f, 1e-8f);
    const float sc = sa * sb;
    float hmax = 0.0f;
#pragma unroll
    for (int fa = 0; fa < 4; ++fa) {
#pragma unroll
      for (int rr = 0; rr < 4; ++rr) {
        const long m = m0 + wm * 64 + fa * 16 + kg * 4 + rr;  // row=(lane>>4)*4+reg
        if (m < Mstore) {
#pragma unroll
          for (int fb = 0; fb < 4; ++fb) {
            const long n = n0 + wn * 64 + fb * 16 + lr;       // col=lane&15
            float v = epi_scale((float)acc[fa][fb][rr], sc, bias[n]);
            v = gelu_exact(v);
            outp[m * (long)ldo + n] = v;
            hmax = fmaxf(hmax, fabsf(v));
          }
        }
      }
    }
    for (int o = 32; o > 0; o >>= 1) hmax = fmaxf(hmax, __shfl_xor(hmax, o));
    if (lane == 0) atomicMax((unsigned*)slots + 3, __float_as_uint(hmax));
  } else {
    float* po = outp + (long)chunk * cstride;
#pragma unroll
    for (int fa = 0; fa < 4; ++fa) {
#pragma unroll
      for (int rr = 0; rr < 4; ++rr) {
        const long m = m0 + wm * 64 + fa * 16 + kg * 4 + rr;
        if (m < Mstore) {
#pragma unroll
          for (int fb = 0; fb < 4; ++fb) {
            const long n = n0 + wn * 64 + fb * 16 + lr;
            po[m * (long)ldo + n] = (float)acc[fa][fb][rr];  // exact ints
          }
        }
      }
    }
  }
}

// ---------------- launch -----------------------------------------------------

extern "C" void kernel_launch(void* const* d_in, const int* in_sizes, int n_in,
                              void* d_out, int out_size, void* d_ws, size_t ws_size,
                              hipStream_t stream) {
  const float* x  = (const float*)d_in[0];
  const float* w1 = (const float*)d_in[1];
  const float* b1 = (const float*)d_in[2];
  const float* w2 = (const float*)d_in[3];
  const float* b2 = (const float*)d_in[4];
  float* out = (float*)d_out;

  const int Ntok = 16 * 197;  // 3152
  const int Mpad = 3328;      // 26 tiles of 128
  const int D = 768, H = 3072;
  const int ldq1 = 832;       // 768 + 3 corr + pad -> 13 BK=64 iters
  const int ldq2 = 3136;      // 3072 + 12 corr + pad -> 49 iters
  const int SPLITK = 4;       // 49 = 4*12 + 1 -> kbase=12, krem=1

  char* ws = (char*)d_ws;
  size_t o = 0;
  unsigned* slots = (unsigned*)(ws + o); o += 256;  // [x, w1, w2, h]
  char* xq  = ws + o; o += (size_t)Mpad * ldq1;
  char* wq1 = ws + o; o += (size_t)H * ldq1;
  char* wq2 = ws + o; o += (size_t)D * ldq2;
  char* hq  = ws + o; o += (size_t)Mpad * ldq2;
  o = (o + 255) & ~(size_t)255;
  // hbuf (f32 h, 38.7MB) and the 4 split-K partial buffers (38.7MB) are never
  // live simultaneously: union them (4 * Ntok*D == Ntok*H exactly).
  float* hbuf = (float*)(ws + o);
  float* partial = (float*)(ws + o); o += (size_t)SPLITK * Ntok * D * 4;
  (void)ws_size; (void)in_sizes; (void)n_in; (void)out_size;

  hipLaunchKernelGGL(init_kernel, dim3(1), dim3(64), 0, stream, slots);

  hipLaunchKernelGGL(absmax3, dim3(512, 3), dim3(256), 0, stream,
                     x, (long)Ntok * D / 4, w1, (long)H * D / 4,
                     w2, (long)D * H / 4, slots);

  hipLaunchKernelGGL(quant_kernel, dim3(Mpad * (D / 256) / 4), dim3(256), 0, stream,
                     x, Ntok, D, ldq1, slots + 0, 1, xq);
  hipLaunchKernelGGL(quant_kernel, dim3(H * (D / 256) / 4), dim3(256), 0, stream,
                     w1, H, D, ldq1, slots + 1, -1, wq1);
  hipLaunchKernelGGL(quant_kernel, dim3(D * (H / 256) / 4), dim3(256), 0, stream,
                     w2, D, H, ldq2, slots + 2, -1, wq2);

  // layer 1: h = gelu(cim(x,w1) + b1), fused absmax(h) -> slots[3]
  hipLaunchKernelGGL((gemm_cim<0>), dim3((Mpad / 128) * (H / 128), 1), dim3(256), 0, stream,
                     xq, wq1, Ntok, ldq1, Mpad / 128, ldq1 / 64, 0,
                     slots, 0, 1, b1, hbuf, H, 0L);

  hipLaunchKernelGGL(quant_kernel, dim3(Mpad * (H / 256) / 4), dim3(256), 0, stream,
                     hbuf, Ntok, H, ldq2, slots + 3, 1, hq);

  // layer 2: split-K x4, private exact-integer partial buffers (union w/ hbuf)
  hipLaunchKernelGGL((gemm_cim<1>), dim3((Mpad / 128) * (D / 128), SPLITK), dim3(256), 0, stream,
                     hq, wq2, Ntok, ldq2, Mpad / 128, (ldq2 / 64) / SPLITK, (ldq2 / 64) % SPLITK,
                     slots, 3, 2, nullptr, partial, D, (long)Ntok * D);

  hipLaunchKernelGGL(epi2_kernel, dim3(1024), dim3(256), 0, stream,
                     partial, (long)Ntok * D, b2, slots, out, (long)Ntok * D / 4);
}